// Round 2
// baseline (1318.670 us; speedup 1.0000x reference)
//
#include <hip/hip_runtime.h>
#include <hip/hip_bf16.h>
#include <math.h>

// ---------------------------------------------------------------------------
// SimpleBetterGCN: h1 = relu(A @ (x@W1+b1)); h2 = relu(A @ (h1@W2+b2));
// h = h1+h2; w = softmax(h@att_w+att_b over nodes); g = sum(w*h); out = g@Wc+bc
// ---------------------------------------------------------------------------

#define HID 128

__device__ __forceinline__ float relu(float v) { return v > 0.f ? v : 0.f; }

// --------------------------- GEMM: [N,K] @ [K,128] -------------------------
template <int K, bool RELU_IN>
__global__ __launch_bounds__(256) void gemm_kernel(
    const float* __restrict__ in, const float* __restrict__ w,
    const float* __restrict__ bias, float* __restrict__ out, int Nrows) {
  __shared__ float w_lds[K * HID];
  __shared__ float in_lds[64 * K];
  const int t = threadIdx.x;
  const int R0 = blockIdx.x * 64;

  for (int idx = t * 4; idx < K * HID; idx += 1024) {
    *(float4*)&w_lds[idx] = *(const float4*)&w[idx];
  }
  const int limit = Nrows * K;
  for (int idx = t * 4; idx < 64 * K; idx += 1024) {
    int g = R0 * K + idx;
    float4 v;
    if (g < limit) {
      v = *(const float4*)&in[g];
    } else {
      v.x = v.y = v.z = v.w = 0.f;
    }
    if (RELU_IN) {
      v.x = relu(v.x); v.y = relu(v.y); v.z = relu(v.z); v.w = relu(v.w);
    }
    *(float4*)&in_lds[idx] = v;
  }
  __syncthreads();

  const int i = t >> 5;
  const int j = t & 31;
  const int r0 = i * 8;
  const int c0 = j * 4;
  float4 bv = *(const float4*)&bias[c0];
  float acc[8][4] = {};

#pragma unroll 4
  for (int k = 0; k < K; ++k) {
    float4 wv = *(const float4*)&w_lds[k * HID + c0];
#pragma unroll
    for (int ii = 0; ii < 8; ++ii) {
      float a = in_lds[(r0 + ii) * K + k];
      acc[ii][0] = fmaf(a, wv.x, acc[ii][0]);
      acc[ii][1] = fmaf(a, wv.y, acc[ii][1]);
      acc[ii][2] = fmaf(a, wv.z, acc[ii][2]);
      acc[ii][3] = fmaf(a, wv.w, acc[ii][3]);
    }
  }

#pragma unroll
  for (int ii = 0; ii < 8; ++ii) {
    int gr = R0 + r0 + ii;
    if (gr < Nrows) {
      float4 o;
      o.x = acc[ii][0] + bv.x;
      o.y = acc[ii][1] + bv.y;
      o.z = acc[ii][2] + bv.z;
      o.w = acc[ii][3] + bv.w;
      *(float4*)&out[(size_t)gr * HID + c0] = o;
    }
  }
}

// --------------------------- SPMM (COO, rows sorted) -----------------------
// out[r,:] += v * mat[c,:].  Half-wave (32 lanes x float4 = 512B) per edge,
// 2 edges per wave-instruction, 2x unroll => 4 edges / 2 gathers in flight.
// Metadata staged per 64-edge batch via per-lane loads + shfl broadcast.
__global__ __launch_bounds__(256) void spmm_kernel(
    const float* __restrict__ mat, const int* __restrict__ rows,
    const int* __restrict__ cols, const float* __restrict__ vals,
    float* __restrict__ out, int E) {
  const int gw = (blockIdx.x * blockDim.x + threadIdx.x) >> 6;
  const int lane = threadIdx.x & 63;
  const int nw = (gridDim.x * blockDim.x) >> 6;
  const int S = (E + nw - 1) / nw;
  int start = gw * S;
  int end = start + S;
  if (end > E) end = E;
  if (start >= end) return;

  const int sw = lane >> 5;           // subwave 0/1: which edge of the pair
  const int d4 = (lane & 31) * 4;     // this lane's 4 dims
  float4 acc = {0.f, 0.f, 0.f, 0.f};
  int curRow = -1;

  auto flush = [&]() {
    float* o = out + (size_t)curRow * HID + d4;
    atomicAdd(o + 0, acc.x);
    atomicAdd(o + 1, acc.y);
    atomicAdd(o + 2, acc.z);
    atomicAdd(o + 3, acc.w);
    acc.x = acc.y = acc.z = acc.w = 0.f;
  };

  for (int base = start; base < end; base += 64) {
    const int cnt = min(64, end - base);
    int c_ = 0, r_ = 0;
    float v_ = 0.f;
    if (lane < cnt) {
      int e = base + lane;
      c_ = cols[e];
      v_ = vals[e];
      r_ = rows[e];
    }

    int j = 0;
    // main: 4 edges per wave-iteration (2 per subwave), 2 gathers in flight
    for (; j + 4 <= cnt; j += 4) {
      int i0 = j + sw, i1 = j + 2 + sw;
      int c0 = __shfl(c_, i0), c1 = __shfl(c_, i1);
      float v0 = __shfl(v_, i0), v1 = __shfl(v_, i1);
      int r0 = __shfl(r_, i0), r1 = __shfl(r_, i1);
      float4 m0 = *(const float4*)(mat + c0 * HID + d4);
      float4 m1 = *(const float4*)(mat + c1 * HID + d4);
      if (r0 != curRow) {
        if (curRow >= 0) flush();
        curRow = r0;
      }
      acc.x = fmaf(v0, m0.x, acc.x);
      acc.y = fmaf(v0, m0.y, acc.y);
      acc.z = fmaf(v0, m0.z, acc.z);
      acc.w = fmaf(v0, m0.w, acc.w);
      if (r1 != curRow) {
        flush();
        curRow = r1;
      }
      acc.x = fmaf(v1, m1.x, acc.x);
      acc.y = fmaf(v1, m1.y, acc.y);
      acc.z = fmaf(v1, m1.z, acc.z);
      acc.w = fmaf(v1, m1.w, acc.w);
    }
    // tail: 2 edges (or 1) per iteration
    for (; j < cnt; j += 2) {
      int i0 = j + sw;
      bool valid = i0 < cnt;
      int idx = valid ? i0 : (cnt - 1);
      int c0 = __shfl(c_, idx);
      float v0 = __shfl(v_, idx);
      int r0 = __shfl(r_, idx);
      if (valid) {
        if (r0 != curRow) {
          if (curRow >= 0) flush();
          curRow = r0;
        }
        float4 m0 = *(const float4*)(mat + c0 * HID + d4);
        acc.x = fmaf(v0, m0.x, acc.x);
        acc.y = fmaf(v0, m0.y, acc.y);
        acc.z = fmaf(v0, m0.z, acc.z);
        acc.w = fmaf(v0, m0.w, acc.w);
      }
    }
  }
  if (curRow >= 0) flush();
}

// --------------------------- attention: per-node scores --------------------
__global__ __launch_bounds__(256) void att_score_kernel(
    const float* __restrict__ h1, const float* __restrict__ h2,
    const float* __restrict__ attw, const float* __restrict__ attb,
    float* __restrict__ s, int N) {
  const int gw = (blockIdx.x * blockDim.x + threadIdx.x) >> 6;
  const int lane = threadIdx.x & 63;
  const int nw = (gridDim.x * blockDim.x) >> 6;
  const float2 w = *(const float2*)(attw + lane * 2);
  const float b = attb[0];

  for (int n = gw; n < N; n += nw) {
    float2 a = *(const float2*)(h1 + (size_t)n * HID + lane * 2);
    float2 c = *(const float2*)(h2 + (size_t)n * HID + lane * 2);
    float hx = relu(a.x) + relu(c.x);
    float hy = relu(a.y) + relu(c.y);
    float p = hx * w.x + hy * w.y;
#pragma unroll
    for (int off = 1; off < 64; off <<= 1) p += __shfl_xor(p, off);
    if (lane == 0) s[n] = p + b;
  }
}

// --------------------------- max over s + zero accumulators -----------------
__global__ __launch_bounds__(1024) void att_max_kernel(
    const float* __restrict__ s, float* __restrict__ small, int N) {
  __shared__ float red[1024];
  const int t = threadIdx.x;
  float m = -INFINITY;
  for (int i = t; i < N; i += 1024) m = fmaxf(m, s[i]);
  red[t] = m;
  __syncthreads();
  for (int off = 512; off > 0; off >>= 1) {
    if (t < off) red[t] = fmaxf(red[t], red[t + off]);
    __syncthreads();
  }
  if (t == 0) small[0] = red[0];
  if (t >= 1 && t < 130) small[t] = 0.f;
}

// --------------------------- weighted sums ---------------------------------
__global__ __launch_bounds__(256) void att_wsum_kernel(
    const float* __restrict__ h1, const float* __restrict__ h2,
    const float* __restrict__ s, float* __restrict__ small, int N) {
  const int gw = (blockIdx.x * blockDim.x + threadIdx.x) >> 6;
  const int lane = threadIdx.x & 63;
  const int nw = (gridDim.x * blockDim.x) >> 6;
  const float m = small[0];

  float2 accn = {0.f, 0.f};
  float accd = 0.f;
  for (int n = gw; n < N; n += nw) {
    float2 a = *(const float2*)(h1 + (size_t)n * HID + lane * 2);
    float2 c = *(const float2*)(h2 + (size_t)n * HID + lane * 2);
    float hx = relu(a.x) + relu(c.x);
    float hy = relu(a.y) + relu(c.y);
    float e = expf(s[n] - m);
    accn.x = fmaf(e, hx, accn.x);
    accn.y = fmaf(e, hy, accn.y);
    accd += e;
  }
  atomicAdd(&small[2 + lane * 2], accn.x);
  atomicAdd(&small[2 + lane * 2 + 1], accn.y);
  if (lane == 0) atomicAdd(&small[1], accd);
}

// --------------------------- final: g = num/den; out = g @ cls_w + cls_b ----
__global__ __launch_bounds__(128) void att_final_kernel(
    const float* __restrict__ small, const float* __restrict__ clsw,
    const float* __restrict__ clsb, float* __restrict__ out) {
  __shared__ float g[HID];
  const int t = threadIdx.x;
  const float den = small[1];
  g[t] = small[2 + t] / den;
  __syncthreads();
  if (t < 10) {
    float acc = clsb[t];
    for (int d = 0; d < HID; ++d) acc = fmaf(g[d], clsw[d * 10 + t], acc);
    out[t] = acc;
  }
}

extern "C" void kernel_launch(void* const* d_in, const int* in_sizes, int n_in,
                              void* d_out, int out_size, void* d_ws,
                              size_t ws_size, hipStream_t stream) {
  const float* x = (const float*)d_in[0];
  const int* erows = (const int*)d_in[1];
  const int* ecols = (const int*)d_in[2];
  const float* evals = (const float*)d_in[3];
  const float* fc1w = (const float*)d_in[4];
  const float* fc1b = (const float*)d_in[5];
  const float* fc2w = (const float*)d_in[6];
  const float* fc2b = (const float*)d_in[7];
  const float* attw = (const float*)d_in[8];
  const float* attb = (const float*)d_in[9];
  const float* clsw = (const float*)d_in[10];
  const float* clsb = (const float*)d_in[11];
  float* out = (float*)d_out;

  const int N = in_sizes[0] / 64;   // 100000
  const int E = in_sizes[1];        // 3200000

  float* ws = (float*)d_ws;
  float* t = ws;                               // [N,128] t1 then t2
  float* h1 = ws + (size_t)N * HID;            // [N,128] pre-relu accum
  float* h2 = ws + (size_t)2 * N * HID;        // [N,128] pre-relu accum
  float* s = ws + (size_t)3 * N * HID;         // [N]
  float* small = s + N;                        // [130]: m, den, num[128]

  hipMemsetAsync(h1, 0, (size_t)2 * N * HID * sizeof(float), stream);

  gemm_kernel<64, false><<<(N + 63) / 64, 256, 0, stream>>>(x, fc1w, fc1b, t, N);
  spmm_kernel<<<2048, 256, 0, stream>>>(t, erows, ecols, evals, h1, E);
  gemm_kernel<128, true><<<(N + 63) / 64, 256, 0, stream>>>(h1, fc2w, fc2b, t, N);
  spmm_kernel<<<2048, 256, 0, stream>>>(t, erows, ecols, evals, h2, E);
  att_score_kernel<<<2048, 256, 0, stream>>>(h1, h2, attw, attb, s, N);
  att_max_kernel<<<1, 1024, 0, stream>>>(s, small, N);
  att_wsum_kernel<<<512, 256, 0, stream>>>(h1, h2, s, small, N);
  att_final_kernel<<<1, 128, 0, stream>>>(small, clsw, clsb, out);
}

// Round 3
// 741.392 us; speedup vs baseline: 1.7786x; 1.7786x over previous
//
#include <hip/hip_runtime.h>
#include <hip/hip_bf16.h>
#include <math.h>

// ---------------------------------------------------------------------------
// SimpleBetterGCN: h1 = relu(A @ (x@W1+b1)); h2 = relu(A @ (h1@W2+b2));
// h = h1+h2; w = softmax(h@att_w+att_b over nodes); g = sum(w*h); out = g@Wc+bc
//
// R3: gather matrix t stored as bf16 (halves the spmm gather bytes — the
// measured ~2.6 TB/s TCC throughput cap is byte-limited, not request-limited).
// spmm reverted to full-wave-per-edge (single curRow => minimal atomic flush
// traffic; R2's half-wave split 4x'd WRITE_SIZE).
// ---------------------------------------------------------------------------

#define HID 128

__device__ __forceinline__ float relu(float v) { return v > 0.f ? v : 0.f; }

// round-to-nearest f32 -> bf16 (finite values)
__device__ __forceinline__ unsigned short f2bf(float f) {
  unsigned u = __float_as_uint(f);
  u += 0x7FFFu + ((u >> 16) & 1u);
  return (unsigned short)(u >> 16);
}

// --------------------------- GEMM: [N,K] @ [K,128] -> bf16 ------------------
template <int K, bool RELU_IN>
__global__ __launch_bounds__(256) void gemm_kernel(
    const float* __restrict__ in, const float* __restrict__ w,
    const float* __restrict__ bias, unsigned short* __restrict__ out,
    int Nrows) {
  __shared__ float w_lds[K * HID];
  __shared__ float in_lds[64 * K];
  const int t = threadIdx.x;
  const int R0 = blockIdx.x * 64;

  for (int idx = t * 4; idx < K * HID; idx += 1024) {
    *(float4*)&w_lds[idx] = *(const float4*)&w[idx];
  }
  const int limit = Nrows * K;
  for (int idx = t * 4; idx < 64 * K; idx += 1024) {
    int g = R0 * K + idx;
    float4 v;
    if (g < limit) {
      v = *(const float4*)&in[g];
    } else {
      v.x = v.y = v.z = v.w = 0.f;
    }
    if (RELU_IN) {
      v.x = relu(v.x); v.y = relu(v.y); v.z = relu(v.z); v.w = relu(v.w);
    }
    *(float4*)&in_lds[idx] = v;
  }
  __syncthreads();

  const int i = t >> 5;
  const int j = t & 31;
  const int r0 = i * 8;
  const int c0 = j * 4;
  float4 bv = *(const float4*)&bias[c0];
  float acc[8][4] = {};

#pragma unroll 4
  for (int k = 0; k < K; ++k) {
    float4 wv = *(const float4*)&w_lds[k * HID + c0];
#pragma unroll
    for (int ii = 0; ii < 8; ++ii) {
      float a = in_lds[(r0 + ii) * K + k];
      acc[ii][0] = fmaf(a, wv.x, acc[ii][0]);
      acc[ii][1] = fmaf(a, wv.y, acc[ii][1]);
      acc[ii][2] = fmaf(a, wv.z, acc[ii][2]);
      acc[ii][3] = fmaf(a, wv.w, acc[ii][3]);
    }
  }

#pragma unroll
  for (int ii = 0; ii < 8; ++ii) {
    int gr = R0 + r0 + ii;
    if (gr < Nrows) {
      ushort4 o;
      o.x = f2bf(acc[ii][0] + bv.x);
      o.y = f2bf(acc[ii][1] + bv.y);
      o.z = f2bf(acc[ii][2] + bv.z);
      o.w = f2bf(acc[ii][3] + bv.w);
      *(ushort4*)&out[(size_t)gr * HID + c0] = o;
    }
  }
}

// --------------------------- SPMM (COO, rows sorted, bf16 mat) --------------
// out[r,:] += v * mat[c,:].  Full wave per edge: 64 lanes x 2 bf16 = 256B/row.
// 4x unroll: 4 gathers hoisted before the accumulate/flush chain.
__global__ __launch_bounds__(256) void spmm_kernel(
    const unsigned short* __restrict__ mat, const int* __restrict__ rows,
    const int* __restrict__ cols, const float* __restrict__ vals,
    float* __restrict__ out, int E) {
  int gw0 = (blockIdx.x * blockDim.x + threadIdx.x) >> 6;
  const int gw = __builtin_amdgcn_readfirstlane(gw0);
  const int lane = threadIdx.x & 63;
  const int nw = (gridDim.x * blockDim.x) >> 6;
  const int S = (E + nw - 1) / nw;
  int start = gw * S;
  int end = start + S;
  if (end > E) end = E;
  if (start >= end) return;

  const int d2 = lane * 2;  // two dims per lane
  float2 acc = {0.f, 0.f};
  int curRow = rows[start];

  auto flush = [&]() {
    float* o = out + (size_t)curRow * HID + d2;
    atomicAdd(o + 0, acc.x);
    atomicAdd(o + 1, acc.y);
    acc.x = 0.f;
    acc.y = 0.f;
  };

  int e = start;
  for (; e + 4 <= end; e += 4) {
    int c0 = cols[e + 0], c1 = cols[e + 1], c2 = cols[e + 2], c3 = cols[e + 3];
    float v0 = vals[e + 0], v1 = vals[e + 1], v2 = vals[e + 2], v3 = vals[e + 3];
    int r0 = rows[e + 0], r1 = rows[e + 1], r2 = rows[e + 2], r3 = rows[e + 3];
    unsigned u0 = *(const unsigned*)(mat + (size_t)c0 * HID + d2);
    unsigned u1 = *(const unsigned*)(mat + (size_t)c1 * HID + d2);
    unsigned u2 = *(const unsigned*)(mat + (size_t)c2 * HID + d2);
    unsigned u3 = *(const unsigned*)(mat + (size_t)c3 * HID + d2);

    if (r0 != curRow) { flush(); curRow = r0; }
    acc.x = fmaf(v0, __uint_as_float(u0 << 16), acc.x);
    acc.y = fmaf(v0, __uint_as_float(u0 & 0xFFFF0000u), acc.y);
    if (r1 != curRow) { flush(); curRow = r1; }
    acc.x = fmaf(v1, __uint_as_float(u1 << 16), acc.x);
    acc.y = fmaf(v1, __uint_as_float(u1 & 0xFFFF0000u), acc.y);
    if (r2 != curRow) { flush(); curRow = r2; }
    acc.x = fmaf(v2, __uint_as_float(u2 << 16), acc.x);
    acc.y = fmaf(v2, __uint_as_float(u2 & 0xFFFF0000u), acc.y);
    if (r3 != curRow) { flush(); curRow = r3; }
    acc.x = fmaf(v3, __uint_as_float(u3 << 16), acc.x);
    acc.y = fmaf(v3, __uint_as_float(u3 & 0xFFFF0000u), acc.y);
  }
  for (; e < end; ++e) {
    int c = cols[e];
    float v = vals[e];
    int r = rows[e];
    if (r != curRow) { flush(); curRow = r; }
    unsigned u = *(const unsigned*)(mat + (size_t)c * HID + d2);
    acc.x = fmaf(v, __uint_as_float(u << 16), acc.x);
    acc.y = fmaf(v, __uint_as_float(u & 0xFFFF0000u), acc.y);
  }
  flush();
}

// --------------------------- attention: per-node scores --------------------
__global__ __launch_bounds__(256) void att_score_kernel(
    const float* __restrict__ h1, const float* __restrict__ h2,
    const float* __restrict__ attw, const float* __restrict__ attb,
    float* __restrict__ s, int N) {
  const int gw = (blockIdx.x * blockDim.x + threadIdx.x) >> 6;
  const int lane = threadIdx.x & 63;
  const int nw = (gridDim.x * blockDim.x) >> 6;
  const float2 w = *(const float2*)(attw + lane * 2);
  const float b = attb[0];

  for (int n = gw; n < N; n += nw) {
    float2 a = *(const float2*)(h1 + (size_t)n * HID + lane * 2);
    float2 c = *(const float2*)(h2 + (size_t)n * HID + lane * 2);
    float hx = relu(a.x) + relu(c.x);
    float hy = relu(a.y) + relu(c.y);
    float p = hx * w.x + hy * w.y;
#pragma unroll
    for (int off = 1; off < 64; off <<= 1) p += __shfl_xor(p, off);
    if (lane == 0) s[n] = p + b;
  }
}

// --------------------------- max over s + zero accumulators -----------------
__global__ __launch_bounds__(1024) void att_max_kernel(
    const float* __restrict__ s, float* __restrict__ small, int N) {
  __shared__ float red[1024];
  const int t = threadIdx.x;
  float m = -INFINITY;
  for (int i = t; i < N; i += 1024) m = fmaxf(m, s[i]);
  red[t] = m;
  __syncthreads();
  for (int off = 512; off > 0; off >>= 1) {
    if (t < off) red[t] = fmaxf(red[t], red[t + off]);
    __syncthreads();
  }
  if (t == 0) small[0] = red[0];
  if (t >= 1 && t < 130) small[t] = 0.f;
}

// --------------------------- weighted sums ---------------------------------
__global__ __launch_bounds__(256) void att_wsum_kernel(
    const float* __restrict__ h1, const float* __restrict__ h2,
    const float* __restrict__ s, float* __restrict__ small, int N) {
  const int gw = (blockIdx.x * blockDim.x + threadIdx.x) >> 6;
  const int lane = threadIdx.x & 63;
  const int nw = (gridDim.x * blockDim.x) >> 6;
  const float m = small[0];

  float2 accn = {0.f, 0.f};
  float accd = 0.f;
  for (int n = gw; n < N; n += nw) {
    float2 a = *(const float2*)(h1 + (size_t)n * HID + lane * 2);
    float2 c = *(const float2*)(h2 + (size_t)n * HID + lane * 2);
    float hx = relu(a.x) + relu(c.x);
    float hy = relu(a.y) + relu(c.y);
    float e = expf(s[n] - m);
    accn.x = fmaf(e, hx, accn.x);
    accn.y = fmaf(e, hy, accn.y);
    accd += e;
  }
  atomicAdd(&small[2 + lane * 2], accn.x);
  atomicAdd(&small[2 + lane * 2 + 1], accn.y);
  if (lane == 0) atomicAdd(&small[1], accd);
}

// --------------------------- final: g = num/den; out = g @ cls_w + cls_b ----
__global__ __launch_bounds__(128) void att_final_kernel(
    const float* __restrict__ small, const float* __restrict__ clsw,
    const float* __restrict__ clsb, float* __restrict__ out) {
  __shared__ float g[HID];
  const int t = threadIdx.x;
  const float den = small[1];
  g[t] = small[2 + t] / den;
  __syncthreads();
  if (t < 10) {
    float acc = clsb[t];
    for (int d = 0; d < HID; ++d) acc = fmaf(g[d], clsw[d * 10 + t], acc);
    out[t] = acc;
  }
}

extern "C" void kernel_launch(void* const* d_in, const int* in_sizes, int n_in,
                              void* d_out, int out_size, void* d_ws,
                              size_t ws_size, hipStream_t stream) {
  const float* x = (const float*)d_in[0];
  const int* erows = (const int*)d_in[1];
  const int* ecols = (const int*)d_in[2];
  const float* evals = (const float*)d_in[3];
  const float* fc1w = (const float*)d_in[4];
  const float* fc1b = (const float*)d_in[5];
  const float* fc2w = (const float*)d_in[6];
  const float* fc2b = (const float*)d_in[7];
  const float* attw = (const float*)d_in[8];
  const float* attb = (const float*)d_in[9];
  const float* clsw = (const float*)d_in[10];
  const float* clsb = (const float*)d_in[11];
  float* out = (float*)d_out;

  const int N = in_sizes[0] / 64;   // 100000
  const int E = in_sizes[1];        // 3200000

  float* ws = (float*)d_ws;
  // layout: h1[N*128] f32 | h2[N*128] f32 | t[N*128] bf16 | s[N] | small[130]
  float* h1 = ws;
  float* h2 = ws + (size_t)N * HID;
  unsigned short* t = (unsigned short*)(ws + (size_t)2 * N * HID);
  float* s = ws + (size_t)2 * N * HID + (size_t)N * HID / 2;
  float* small = s + N;

  // Zero both spmm accumulators (contiguous region)
  hipMemsetAsync(h1, 0, (size_t)2 * N * HID * sizeof(float), stream);

  // t1 = bf16(x @ fc1_w + fc1_b)
  gemm_kernel<64, false><<<(N + 63) / 64, 256, 0, stream>>>(x, fc1w, fc1b, t, N);
  // h1acc = A @ t1
  spmm_kernel<<<2048, 256, 0, stream>>>(t, erows, ecols, evals, h1, E);
  // t2 = bf16(relu(h1acc) @ fc2_w + fc2_b)
  gemm_kernel<128, true><<<(N + 63) / 64, 256, 0, stream>>>(h1, fc2w, fc2b, t, N);
  // h2acc = A @ t2
  spmm_kernel<<<2048, 256, 0, stream>>>(t, erows, ecols, evals, h2, E);
  // scores
  att_score_kernel<<<2048, 256, 0, stream>>>(h1, h2, attw, attb, s, N);
  // max + zero num/den
  att_max_kernel<<<1, 1024, 0, stream>>>(s, small, N);
  // weighted sums
  att_wsum_kernel<<<512, 256, 0, stream>>>(h1, h2, s, small, N);
  // final 10-class output
  att_final_kernel<<<1, 128, 0, stream>>>(small, clsw, clsb, out);
}

// Round 4
// 580.488 us; speedup vs baseline: 2.2717x; 1.2772x over previous
//
#include <hip/hip_runtime.h>
#include <hip/hip_bf16.h>
#include <math.h>

// ---------------------------------------------------------------------------
// SimpleBetterGCN.
// R4 structure:
//   xb  = bf16(x)                                   [N,64]
//   ax  = A @ xb (spmm1, 2 lines/edge), rs = rowsum(A)
//   h1r = relu(ax@W1 + rs*b1)          (bf16)       [N,128]
//   t2  = bf16(h1r@W2 + b2)                          [N,128]
//   h2p = A @ t2 (spmm2, 4 lines/edge)  f32          [N,128]
//   s   = (h1r + relu(h2p)) @ att_w + b; softmax over N; g = sum(w*h)
//   out = g @ cls_w + cls_b
// spmm cap is fabric line-request rate (~34 G lines/s measured R1/R3), so
// lever #1 is fewer lines/edge: layer-1 gather commuted to pre-GEMM x (bf16,
// 2 lines/edge instead of 4).
// ---------------------------------------------------------------------------

#define HID 128

__device__ __forceinline__ float relu(float v) { return v > 0.f ? v : 0.f; }

__device__ __forceinline__ unsigned short f2bf(float f) {
  unsigned u = __float_as_uint(f);
  u += 0x7FFFu + ((u >> 16) & 1u);
  return (unsigned short)(u >> 16);
}
__device__ __forceinline__ float bflo(unsigned u) {  // element at lower addr
  return __uint_as_float(u << 16);
}
__device__ __forceinline__ float bfhi(unsigned u) {  // element at higher addr
  return __uint_as_float(u & 0xFFFF0000u);
}

// --------------------------- cast x -> bf16 --------------------------------
__global__ __launch_bounds__(256) void cast_x_kernel(
    const float* __restrict__ x, unsigned short* __restrict__ xb, int n4) {
  int idx = blockIdx.x * 256 + threadIdx.x;
  if (idx < n4) {
    float4 v = *(const float4*)&x[idx * 4];
    ushort4 o;
    o.x = f2bf(v.x); o.y = f2bf(v.y); o.z = f2bf(v.z); o.w = f2bf(v.w);
    *(ushort4*)&xb[idx * 4] = o;
  }
}

// --------------------------- SPMM1 (64-dim bf16 gather) --------------------
// ax[r,:] += v * xb[c,:]; rs[r] += v.  One dim per lane (128B row, 2 lines).
__global__ __launch_bounds__(256) void spmm1_kernel(
    const unsigned short* __restrict__ mat, const int* __restrict__ rows,
    const int* __restrict__ cols, const float* __restrict__ vals,
    float* __restrict__ ax, float* __restrict__ rs, int E) {
  int gw0 = (blockIdx.x * blockDim.x + threadIdx.x) >> 6;
  const int gw = __builtin_amdgcn_readfirstlane(gw0);
  const int lane = threadIdx.x & 63;
  const int nw = (gridDim.x * blockDim.x) >> 6;
  const int S = (E + nw - 1) / nw;
  int start = gw * S;
  int end = start + S;
  if (end > E) end = E;
  if (start >= end) return;

  float acc = 0.f, accv = 0.f;
  int curRow = rows[start];

  auto flush = [&]() {
    atomicAdd(ax + (size_t)curRow * 64 + lane, acc);
    if (lane == 0) atomicAdd(rs + curRow, accv);
    acc = 0.f;
    accv = 0.f;
  };

  int e = start;
  for (; e + 4 <= end; e += 4) {
    int c0 = cols[e + 0], c1 = cols[e + 1], c2 = cols[e + 2], c3 = cols[e + 3];
    float v0 = vals[e + 0], v1 = vals[e + 1], v2 = vals[e + 2], v3 = vals[e + 3];
    int r0 = rows[e + 0], r1 = rows[e + 1], r2 = rows[e + 2], r3 = rows[e + 3];
    unsigned u0 = mat[(size_t)c0 * 64 + lane];
    unsigned u1 = mat[(size_t)c1 * 64 + lane];
    unsigned u2 = mat[(size_t)c2 * 64 + lane];
    unsigned u3 = mat[(size_t)c3 * 64 + lane];

    if (r0 != curRow) { flush(); curRow = r0; }
    acc = fmaf(v0, bflo(u0), acc); accv += v0;
    if (r1 != curRow) { flush(); curRow = r1; }
    acc = fmaf(v1, bflo(u1), acc); accv += v1;
    if (r2 != curRow) { flush(); curRow = r2; }
    acc = fmaf(v2, bflo(u2), acc); accv += v2;
    if (r3 != curRow) { flush(); curRow = r3; }
    acc = fmaf(v3, bflo(u3), acc); accv += v3;
  }
  for (; e < end; ++e) {
    int c = cols[e];
    float v = vals[e];
    int r = rows[e];
    if (r != curRow) { flush(); curRow = r; }
    unsigned u = mat[(size_t)c * 64 + lane];
    acc = fmaf(v, bflo(u), acc); accv += v;
  }
  flush();
}

// --------------------------- gemm1b: h1r = relu(ax@W1 + rs*b1) (bf16) ------
__global__ __launch_bounds__(256) void gemm1_kernel(
    const float* __restrict__ ax, const float* __restrict__ w1,
    const float* __restrict__ b1, const float* __restrict__ rs,
    unsigned short* __restrict__ h1r, int N) {
  __shared__ float w_lds[64 * HID];     // 32 KB
  __shared__ float in_lds[64 * 64];     // 16 KB
  __shared__ float rs_lds[64];
  const int t = threadIdx.x;
  const int R0 = blockIdx.x * 64;

  for (int idx = t * 4; idx < 64 * HID; idx += 1024)
    *(float4*)&w_lds[idx] = *(const float4*)&w1[idx];
  const int limit = N * 64;
  for (int idx = t * 4; idx < 64 * 64; idx += 1024) {
    int g = R0 * 64 + idx;
    float4 v;
    if (g < limit) v = *(const float4*)&ax[g];
    else { v.x = v.y = v.z = v.w = 0.f; }
    *(float4*)&in_lds[idx] = v;
  }
  if (t < 64) {
    int gr = R0 + t;
    rs_lds[t] = gr < N ? rs[gr] : 0.f;
  }
  __syncthreads();

  const int i = t >> 5, j = t & 31;
  const int r0 = i * 8, c0 = j * 4;
  float4 bv = *(const float4*)&b1[c0];
  float acc[8][4] = {};

#pragma unroll 4
  for (int k = 0; k < 64; ++k) {
    float4 wv = *(const float4*)&w_lds[k * HID + c0];
#pragma unroll
    for (int ii = 0; ii < 8; ++ii) {
      float a = in_lds[(r0 + ii) * 64 + k];
      acc[ii][0] = fmaf(a, wv.x, acc[ii][0]);
      acc[ii][1] = fmaf(a, wv.y, acc[ii][1]);
      acc[ii][2] = fmaf(a, wv.z, acc[ii][2]);
      acc[ii][3] = fmaf(a, wv.w, acc[ii][3]);
    }
  }

#pragma unroll
  for (int ii = 0; ii < 8; ++ii) {
    int gr = R0 + r0 + ii;
    if (gr < N) {
      float rsv = rs_lds[r0 + ii];
      ushort4 o;
      o.x = f2bf(relu(acc[ii][0] + rsv * bv.x));
      o.y = f2bf(relu(acc[ii][1] + rsv * bv.y));
      o.z = f2bf(relu(acc[ii][2] + rsv * bv.z));
      o.w = f2bf(relu(acc[ii][3] + rsv * bv.w));
      *(ushort4*)&h1r[(size_t)gr * HID + c0] = o;
    }
  }
}

// --------------------------- gemm2: t2 = bf16(h1r@W2 + b2) -----------------
// bf16 LDS staging (48 KB total -> 3 blocks/CU; R3's f32 version was 96 KB
// -> 1 block/CU = 1 wave/SIMD, staging-latency bound).
__global__ __launch_bounds__(256) void gemm2_kernel(
    const unsigned short* __restrict__ h1r, const float* __restrict__ w2,
    const float* __restrict__ b2, unsigned short* __restrict__ t2, int N) {
  __shared__ unsigned short w_lds[HID * HID];   // 32 KB
  __shared__ unsigned short in_lds[64 * HID];   // 16 KB
  const int t = threadIdx.x;
  const int R0 = blockIdx.x * 64;

  for (int idx = t * 4; idx < HID * HID; idx += 1024) {
    float4 v = *(const float4*)&w2[idx];
    ushort4 o;
    o.x = f2bf(v.x); o.y = f2bf(v.y); o.z = f2bf(v.z); o.w = f2bf(v.w);
    *(ushort4*)&w_lds[idx] = o;
  }
  const size_t limit = (size_t)N * HID;
  for (int idx = t * 8; idx < 64 * HID; idx += 2048) {
    size_t g = (size_t)R0 * HID + idx;
    uint4 v;
    if (g < limit) v = *(const uint4*)&h1r[g];
    else { v.x = v.y = v.z = v.w = 0u; }
    *(uint4*)&in_lds[idx] = v;
  }
  __syncthreads();

  const int i = t >> 5, j = t & 31;
  const int r0 = i * 8, c0 = j * 4;
  float acc[8][4] = {};

#pragma unroll 2
  for (int k = 0; k < HID; k += 2) {
    ushort4 wu0 = *(const ushort4*)&w_lds[k * HID + c0];
    ushort4 wu1 = *(const ushort4*)&w_lds[(k + 1) * HID + c0];
    float w0x = bflo(wu0.x), w0y = bflo(wu0.y), w0z = bflo(wu0.z), w0w = bflo(wu0.w);
    float w1x = bflo(wu1.x), w1y = bflo(wu1.y), w1z = bflo(wu1.z), w1w = bflo(wu1.w);
#pragma unroll
    for (int ii = 0; ii < 8; ++ii) {
      unsigned au = *(const unsigned*)&in_lds[(r0 + ii) * HID + k];
      float a0 = bflo(au), a1 = bfhi(au);
      acc[ii][0] = fmaf(a1, w1x, fmaf(a0, w0x, acc[ii][0]));
      acc[ii][1] = fmaf(a1, w1y, fmaf(a0, w0y, acc[ii][1]));
      acc[ii][2] = fmaf(a1, w1z, fmaf(a0, w0z, acc[ii][2]));
      acc[ii][3] = fmaf(a1, w1w, fmaf(a0, w0w, acc[ii][3]));
    }
  }

  float4 bv = *(const float4*)&b2[c0];
#pragma unroll
  for (int ii = 0; ii < 8; ++ii) {
    int gr = R0 + r0 + ii;
    if (gr < N) {
      ushort4 o;
      o.x = f2bf(acc[ii][0] + bv.x);
      o.y = f2bf(acc[ii][1] + bv.y);
      o.z = f2bf(acc[ii][2] + bv.z);
      o.w = f2bf(acc[ii][3] + bv.w);
      *(ushort4*)&t2[(size_t)gr * HID + c0] = o;
    }
  }
}

// --------------------------- SPMM2 (128-dim bf16 gather) -------------------
__global__ __launch_bounds__(256) void spmm2_kernel(
    const unsigned short* __restrict__ mat, const int* __restrict__ rows,
    const int* __restrict__ cols, const float* __restrict__ vals,
    float* __restrict__ out, int E) {
  int gw0 = (blockIdx.x * blockDim.x + threadIdx.x) >> 6;
  const int gw = __builtin_amdgcn_readfirstlane(gw0);
  const int lane = threadIdx.x & 63;
  const int nw = (gridDim.x * blockDim.x) >> 6;
  const int S = (E + nw - 1) / nw;
  int start = gw * S;
  int end = start + S;
  if (end > E) end = E;
  if (start >= end) return;

  const int d2 = lane * 2;
  float2 acc = {0.f, 0.f};
  int curRow = rows[start];

  auto flush = [&]() {
    float* o = out + (size_t)curRow * HID + d2;
    atomicAdd(o + 0, acc.x);
    atomicAdd(o + 1, acc.y);
    acc.x = 0.f;
    acc.y = 0.f;
  };

  int e = start;
  for (; e + 4 <= end; e += 4) {
    int c0 = cols[e + 0], c1 = cols[e + 1], c2 = cols[e + 2], c3 = cols[e + 3];
    float v0 = vals[e + 0], v1 = vals[e + 1], v2 = vals[e + 2], v3 = vals[e + 3];
    int r0 = rows[e + 0], r1 = rows[e + 1], r2 = rows[e + 2], r3 = rows[e + 3];
    unsigned u0 = *(const unsigned*)(mat + (size_t)c0 * HID + d2);
    unsigned u1 = *(const unsigned*)(mat + (size_t)c1 * HID + d2);
    unsigned u2 = *(const unsigned*)(mat + (size_t)c2 * HID + d2);
    unsigned u3 = *(const unsigned*)(mat + (size_t)c3 * HID + d2);

    if (r0 != curRow) { flush(); curRow = r0; }
    acc.x = fmaf(v0, bflo(u0), acc.x);
    acc.y = fmaf(v0, bfhi(u0), acc.y);
    if (r1 != curRow) { flush(); curRow = r1; }
    acc.x = fmaf(v1, bflo(u1), acc.x);
    acc.y = fmaf(v1, bfhi(u1), acc.y);
    if (r2 != curRow) { flush(); curRow = r2; }
    acc.x = fmaf(v2, bflo(u2), acc.x);
    acc.y = fmaf(v2, bfhi(u2), acc.y);
    if (r3 != curRow) { flush(); curRow = r3; }
    acc.x = fmaf(v3, bflo(u3), acc.x);
    acc.y = fmaf(v3, bfhi(u3), acc.y);
  }
  for (; e < end; ++e) {
    int c = cols[e];
    float v = vals[e];
    int r = rows[e];
    if (r != curRow) { flush(); curRow = r; }
    unsigned u = *(const unsigned*)(mat + (size_t)c * HID + d2);
    acc.x = fmaf(v, bflo(u), acc.x);
    acc.y = fmaf(v, bfhi(u), acc.y);
  }
  flush();
}

// --------------------------- scores + block max ----------------------------
// s[n] = (h1r[n] + relu(h2p[n])) . att_w + b;  partial[blk] = max over rows.
__global__ __launch_bounds__(256) void att_score_kernel(
    const unsigned short* __restrict__ h1r, const float* __restrict__ h2p,
    const float* __restrict__ attw, const float* __restrict__ attb,
    float* __restrict__ s, float* __restrict__ partial, int N) {
  __shared__ float red[4];
  const int gw = (blockIdx.x * blockDim.x + threadIdx.x) >> 6;
  const int lane = threadIdx.x & 63;
  const int nw = (gridDim.x * blockDim.x) >> 6;
  const float2 w = *(const float2*)(attw + lane * 2);
  const float b = attb[0];

  float wm = -INFINITY;
  for (int n = gw; n < N; n += nw) {
    unsigned hu = *(const unsigned*)&h1r[(size_t)n * HID + lane * 2];
    float2 c = *(const float2*)&h2p[(size_t)n * HID + lane * 2];
    float hx = bflo(hu) + relu(c.x);
    float hy = bfhi(hu) + relu(c.y);
    float p = hx * w.x + hy * w.y;
#pragma unroll
    for (int off = 1; off < 64; off <<= 1) p += __shfl_xor(p, off);
    float sc = p + b;
    if (lane == 0) s[n] = sc;
    wm = fmaxf(wm, sc);
  }
  if (lane == 0) red[threadIdx.x >> 6] = wm;
  __syncthreads();
  if (threadIdx.x == 0) {
    float m = fmaxf(fmaxf(red[0], red[1]), fmaxf(red[2], red[3]));
    partial[blockIdx.x] = m;
  }
}

// --------------------------- final max + zero accumulators -----------------
__global__ __launch_bounds__(1024) void att_max_kernel(
    const float* __restrict__ partial, float* __restrict__ small) {
  __shared__ float red[1024];
  const int t = threadIdx.x;
  red[t] = partial[t];
  __syncthreads();
  for (int off = 512; off > 0; off >>= 1) {
    if (t < off) red[t] = fmaxf(red[t], red[t + off]);
    __syncthreads();
  }
  if (t == 0) small[0] = red[0];
  if (t >= 1 && t < 130) small[t] = 0.f;
}

// --------------------------- weighted sums (hierarchical atomics) ----------
__global__ __launch_bounds__(256) void att_wsum_kernel(
    const unsigned short* __restrict__ h1r, const float* __restrict__ h2p,
    const float* __restrict__ s, float* __restrict__ small, int N) {
  __shared__ float blk[130];  // [0]=den, [1..128]=num
  const int t = threadIdx.x;
  const int gw = (blockIdx.x * blockDim.x + t) >> 6;
  const int lane = t & 63;
  const int nw = (gridDim.x * blockDim.x) >> 6;
  const float m = small[0];

  if (t < 130) blk[t] = 0.f;
  __syncthreads();

  float2 accn = {0.f, 0.f};
  float accd = 0.f;
  for (int n = gw; n < N; n += nw) {
    unsigned hu = *(const unsigned*)&h1r[(size_t)n * HID + lane * 2];
    float2 c = *(const float2*)&h2p[(size_t)n * HID + lane * 2];
    float hx = bflo(hu) + relu(c.x);
    float hy = bfhi(hu) + relu(c.y);
    float e = expf(s[n] - m);
    accn.x = fmaf(e, hx, accn.x);
    accn.y = fmaf(e, hy, accn.y);
    accd += e;
  }
  atomicAdd(&blk[1 + lane * 2], accn.x);
  atomicAdd(&blk[2 + lane * 2], accn.y);
  if (lane == 0) atomicAdd(&blk[0], accd);
  __syncthreads();
  if (t < 129) atomicAdd(&small[1 + t], blk[t]);
}

// --------------------------- final classifier ------------------------------
__global__ __launch_bounds__(128) void att_final_kernel(
    const float* __restrict__ small, const float* __restrict__ clsw,
    const float* __restrict__ clsb, float* __restrict__ out) {
  __shared__ float g[HID];
  const int t = threadIdx.x;
  const float den = small[1];
  g[t] = small[2 + t] / den;
  __syncthreads();
  if (t < 10) {
    float acc = clsb[t];
    for (int d = 0; d < HID; ++d) acc = fmaf(g[d], clsw[d * 10 + t], acc);
    out[t] = acc;
  }
}

extern "C" void kernel_launch(void* const* d_in, const int* in_sizes, int n_in,
                              void* d_out, int out_size, void* d_ws,
                              size_t ws_size, hipStream_t stream) {
  const float* x = (const float*)d_in[0];
  const int* erows = (const int*)d_in[1];
  const int* ecols = (const int*)d_in[2];
  const float* evals = (const float*)d_in[3];
  const float* fc1w = (const float*)d_in[4];
  const float* fc1b = (const float*)d_in[5];
  const float* fc2w = (const float*)d_in[6];
  const float* fc2b = (const float*)d_in[7];
  const float* attw = (const float*)d_in[8];
  const float* attb = (const float*)d_in[9];
  const float* clsw = (const float*)d_in[10];
  const float* clsb = (const float*)d_in[11];
  float* out = (float*)d_out;

  const int N = in_sizes[0] / 64;   // 100000
  const int E = in_sizes[1];        // 3200000

  char* base = (char*)d_ws;
  float* ax = (float*)base;                                      // N*64 f32
  float* h2p = (float*)(base + (size_t)N * 64 * 4);              // N*128 f32
  float* rs = (float*)(base + (size_t)N * (64 + 128) * 4);       // N f32
  unsigned short* xb = (unsigned short*)(base + (size_t)N * (64 + 128 + 1) * 4);
  unsigned short* t2 = (unsigned short*)((char*)xb + (size_t)N * 64 * 2);
  unsigned short* h1r = (unsigned short*)((char*)t2 + (size_t)N * HID * 2);
  float* s = (float*)((char*)h1r + (size_t)N * HID * 2);         // N f32
  float* partial = s + N;                                        // 1024 f32
  float* small = partial + 1024;                                 // 130 f32

  const int nblk = (N + 63) / 64;

  // Zero accumulators: ax | h2p | rs are contiguous.
  hipMemsetAsync(ax, 0, (size_t)N * (64 + 128 + 1) * 4, stream);

  cast_x_kernel<<<(N * 64 / 4 + 255) / 256, 256, 0, stream>>>(x, xb, N * 16);
  spmm1_kernel<<<2048, 256, 0, stream>>>(xb, erows, ecols, evals, ax, rs, E);
  gemm1_kernel<<<nblk, 256, 0, stream>>>(ax, fc1w, fc1b, rs, h1r, N);
  gemm2_kernel<<<nblk, 256, 0, stream>>>(h1r, fc2w, fc2b, t2, N);
  spmm2_kernel<<<2048, 256, 0, stream>>>(t2, erows, ecols, evals, h2p, E);
  att_score_kernel<<<1024, 256, 0, stream>>>(h1r, h2p, attw, attb, s, partial, N);
  att_max_kernel<<<1, 1024, 0, stream>>>(partial, small);
  att_wsum_kernel<<<512, 256, 0, stream>>>(h1r, h2p, s, small, N);
  att_final_kernel<<<1, 128, 0, stream>>>(small, clsw, clsb, out);
}